// Round 6
// baseline (5773.850 us; speedup 1.0000x reference)
//
#include <hip/hip_runtime.h>
#include <math.h>

typedef __attribute__((ext_vector_type(8))) short short8;
typedef __attribute__((ext_vector_type(4))) float floatx4;
typedef unsigned short ushort_t;
typedef unsigned int uint32;
typedef unsigned long long u64;

#define BB 256
#define TT 250
#define NS 500
#define HH 512
#define NBLK 256
#define TBLK 256
#define PL_USH 131072u      // act plane: 16ch*16ct*64lane*8 ushorts (512K x 256 bf16)
#define CH_USH 8192u        // act chunk stride: 16ct*64*8
#define WHI_USH 32768
#define SMEMB 131072        // weights hi+lo only; epilogue reuses the same region

// ---- bf16 split helpers (RNE) ----
__device__ __forceinline__ ushort_t f2bf(float f) {
    uint32 u = __float_as_uint(f);
    u += 0x7fffu + ((u >> 16) & 1u);
    return (ushort_t)(u >> 16);
}
__device__ __forceinline__ float bf2f(ushort_t h) { return __uint_as_float(((uint32)h) << 16); }
__device__ __forceinline__ float sigm(float x) { return 1.f / (1.f + expf(-x)); }
__device__ __forceinline__ floatx4 mfma16(short8 a, short8 b, floatx4 c) {
    return __builtin_amdgcn_mfma_f32_16x16x32_bf16(a, b, c, 0, 0, 0);
}
__device__ __forceinline__ u64 pack4(const ushort_t* a) {
    return (u64)a[0] | ((u64)a[1] << 16) | ((u64)a[2] << 32) | ((u64)a[3] << 48);
}
// ---- sync-flag primitives (sc1 path, L3-coherent) ----
__device__ __forceinline__ void st_flag(unsigned* p, unsigned v) {
    __hip_atomic_store(p, v, __ATOMIC_RELAXED, __HIP_MEMORY_SCOPE_AGENT);
}
__device__ __forceinline__ unsigned ld_flag(const unsigned* p) {
    return __hip_atomic_load(p, __ATOMIC_RELAXED, __HIP_MEMORY_SCOPE_AGENT);
}

// flags region layout (u32 index; each logical slot 64B-padded = <<4):
//   [0..4095]      per-block arrival flags   (bid<<4)
//   [4096..]       per-XCD wb-done           (4096 + (xcd<<4))
//   [8192..]       per-XCD inv-done          (8192 + (xcd<<4))
//   [12288..]      per-XCD member count      (12288 + (xcd<<4))
//   [16384..16895] member bids, stride 64    (16384 + xcd*64 + slot)

// ---- flat one-round barrier (init only): thread j polls block j's flag ----
__device__ __forceinline__ void dbar_flat(unsigned* flags, unsigned phase, int bid) {
    __syncthreads();
    if (threadIdx.x == 0) st_flag(flags + ((size_t)bid << 4), phase);
    unsigned* sp = flags + ((size_t)threadIdx.x << 4);
    while (ld_flag(sp) < phase) __builtin_amdgcn_s_sleep(2);
    __syncthreads();
}

// ---- main barrier: arrival + per-XCD leader wbl2 -> global flush -> per-XCD inv ----
// Pack stores are plain write-back (dirty in producer L2). Leader flushes its XCD L2 to
// MALL once (release fence), waits for all XCDs flushed, invalidates its L2 once
// (acquire fence), publishes. GEMM reads are sc0 (L1-bypass, L2-alloc) => coherent.
__device__ __forceinline__ void dbar2(unsigned* flags, unsigned phase, int bid,
                                      int myxcd, bool isLead, unsigned cnt,
                                      unsigned mymem, bool wact) {
    unsigned* wbdone  = flags + 4096;
    unsigned* invdone = flags + 8192;
    __syncthreads();   // drain this block's pack stores to L2 (vmcnt(0) before s_barrier)
    if (threadIdx.x == 0) st_flag(flags + ((size_t)bid << 4), phase);
    if (isLead) {
        if (threadIdx.x < cnt) {   // wait own-XCD members (cnt <= 64)
            unsigned* sp = flags + ((size_t)mymem << 4);
            while (ld_flag(sp) < phase) __builtin_amdgcn_s_sleep(2);
        }
        __syncthreads();
        if (threadIdx.x == 0) {
            __builtin_amdgcn_fence(__ATOMIC_RELEASE, "agent");   // one buffer_wbl2
            st_flag(wbdone + ((size_t)myxcd << 4), phase);
        }
        if (threadIdx.x < 8 && wact) {   // wait all active XCDs flushed
            unsigned* sp = wbdone + ((size_t)threadIdx.x << 4);
            while (ld_flag(sp) < phase) __builtin_amdgcn_s_sleep(2);
        }
        __syncthreads();
        if (threadIdx.x == 0) {
            __builtin_amdgcn_fence(__ATOMIC_ACQUIRE, "agent");   // one buffer_inv
            st_flag(invdone + ((size_t)myxcd << 4), phase);
        }
        __syncthreads();
    } else {
        if (threadIdx.x == 0) {
            unsigned* sp = invdone + ((size_t)myxcd << 4);
            while (ld_flag(sp) < phase) __builtin_amdgcn_s_sleep(2);
        }
        __syncthreads();
    }
}

// ---------------- block reductions (256 thr = 4 waves) ----------------
__device__ __forceinline__ float block_max4(float v, float* scr) {
#pragma unroll
    for (int off = 32; off; off >>= 1) v = fmaxf(v, __shfl_down(v, off, 64));
    if ((threadIdx.x & 63) == 0) scr[threadIdx.x >> 6] = v;
    __syncthreads();
    if (threadIdx.x == 0)
        scr[8] = fmaxf(fmaxf(scr[0], scr[1]), fmaxf(scr[2], scr[3]));
    __syncthreads();
    float r = scr[8];
    __syncthreads();
    return r;
}
__device__ __forceinline__ float2 block_sum2_4(float a, float b, float* scr) {
#pragma unroll
    for (int off = 32; off; off >>= 1) {
        a += __shfl_down(a, off, 64);
        b += __shfl_down(b, off, 64);
    }
    if ((threadIdx.x & 63) == 0) { int w = threadIdx.x >> 6; scr[w] = a; scr[4 + w] = b; }
    __syncthreads();
    if (threadIdx.x == 0) {
        scr[8] = scr[0] + scr[1] + scr[2] + scr[3];
        scr[9] = scr[4] + scr[5] + scr[6] + scr[7];
    }
    __syncthreads();
    float2 r = make_float2(scr[8], scr[9]);
    __syncthreads();
    return r;
}

// ------------- fused gi+gh GEMM: 32 chunks of K=32 ------------------------------------
// Hand-held pipeline: asm global_load_dwordx4 (sc0 = L1-bypass, L2-CACHED) into a
// 12-slot ring (depth 11 = 44 loads in flight), counted s_waitcnt vmcnt(N) +
// sched_barrier before each chunk's MFMAs. Weights double-buffered one chunk ahead.
__device__ __forceinline__ void gemm_both(const ushort_t* __restrict__ gp,
                                          const ushort_t* __restrict__ hp,
                                          const ushort_t* whiS, const ushort_t* wloS,
                                          floatx4 (&aGI)[2][2], floatx4 (&aGH)[2][2]) {
    short8 Bh0[12], Bh1[12], Bl0[12], Bl1[12];
    const ushort_t* gpl = gp + PL_USH;
    const ushort_t* hpl = hp + PL_USH;

#define ISSUE(pc) do {                                                                    \
        const ushort_t* _ph = ((pc) < 16) ? (gp + (size_t)(pc) * CH_USH)                  \
                                          : (hp + (size_t)((pc) - 16) * CH_USH);          \
        const ushort_t* _pl = ((pc) < 16) ? (gpl + (size_t)(pc) * CH_USH)                 \
                                          : (hpl + (size_t)((pc) - 16) * CH_USH);         \
        asm volatile("global_load_dwordx4 %0, %1, off sc0"                                \
                     : "=v"(Bh0[(pc) % 12]) : "v"(_ph));                                  \
        asm volatile("global_load_dwordx4 %0, %1, off offset:1024 sc0"                    \
                     : "=v"(Bh1[(pc) % 12]) : "v"(_ph));                                  \
        asm volatile("global_load_dwordx4 %0, %1, off sc0"                                \
                     : "=v"(Bl0[(pc) % 12]) : "v"(_pl));                                  \
        asm volatile("global_load_dwordx4 %0, %1, off offset:1024 sc0"                    \
                     : "=v"(Bl1[(pc) % 12]) : "v"(_pl));                                  \
    } while (0)

    ISSUE(0); ISSUE(1); ISSUE(2); ISSUE(3); ISSUE(4); ISSUE(5);
    ISSUE(6); ISSUE(7); ISSUE(8); ISSUE(9); ISSUE(10);

    short8 w0h = *(const short8*)(whiS);
    short8 w1h = *(const short8*)(whiS + 512);
    short8 w0l = *(const short8*)(wloS);
    short8 w1l = *(const short8*)(wloS + 512);

#define GSTEP(c, N) do {                                                                  \
        if ((c) + 11 < 32) ISSUE((c) + 11);                                               \
        short8 n0h, n1h, n0l, n1l;                                                        \
        if ((c) + 1 < 32) {                                                               \
            const size_t _w = (size_t)(((c) + 1) * 2) * 512;                              \
            n0h = *(const short8*)(whiS + _w);                                            \
            n1h = *(const short8*)(whiS + _w + 512);                                      \
            n0l = *(const short8*)(wloS + _w);                                            \
            n1l = *(const short8*)(wloS + _w + 512);                                      \
        }                                                                                 \
        asm volatile("s_waitcnt vmcnt(" #N ")" ::: "memory");                             \
        __builtin_amdgcn_sched_barrier(0);                                                \
        const int _cs = (c) % 12;                                                         \
        floatx4 (&A)[2][2] = ((c) < 16) ? aGI : aGH;                                      \
        A[0][0] = mfma16(w0h, Bh0[_cs], A[0][0]);                                         \
        A[0][1] = mfma16(w0h, Bh1[_cs], A[0][1]);                                         \
        A[1][0] = mfma16(w1h, Bh0[_cs], A[1][0]);                                         \
        A[1][1] = mfma16(w1h, Bh1[_cs], A[1][1]);                                         \
        A[0][0] = mfma16(w0h, Bl0[_cs], A[0][0]);                                         \
        A[0][1] = mfma16(w0h, Bl1[_cs], A[0][1]);                                         \
        A[1][0] = mfma16(w1h, Bl0[_cs], A[1][0]);                                         \
        A[1][1] = mfma16(w1h, Bl1[_cs], A[1][1]);                                         \
        A[0][0] = mfma16(w0l, Bh0[_cs], A[0][0]);                                         \
        A[0][1] = mfma16(w0l, Bh1[_cs], A[0][1]);                                         \
        A[1][0] = mfma16(w1l, Bh0[_cs], A[1][0]);                                         \
        A[1][1] = mfma16(w1l, Bh1[_cs], A[1][1]);                                         \
        if ((c) + 1 < 32) { w0h = n0h; w1h = n1h; w0l = n0l; w1l = n1l; }                 \
    } while (0)

    GSTEP(0, 44);  GSTEP(1, 44);  GSTEP(2, 44);  GSTEP(3, 44);  GSTEP(4, 44);
    GSTEP(5, 44);  GSTEP(6, 44);  GSTEP(7, 44);  GSTEP(8, 44);  GSTEP(9, 44);
    GSTEP(10, 44); GSTEP(11, 44); GSTEP(12, 44); GSTEP(13, 44); GSTEP(14, 44);
    GSTEP(15, 44); GSTEP(16, 44); GSTEP(17, 44); GSTEP(18, 44); GSTEP(19, 44);
    GSTEP(20, 44); GSTEP(21, 40); GSTEP(22, 36); GSTEP(23, 32); GSTEP(24, 28);
    GSTEP(25, 24); GSTEP(26, 20); GSTEP(27, 16); GSTEP(28, 12); GSTEP(29, 8);
    GSTEP(30, 4);  GSTEP(31, 0);
#undef GSTEP
#undef ISSUE
}

// ---------------- main persistent kernel ----------------
// 256 blocks = L(2) x UG(64 groups of 8 units) x CT(2 col-halves of 128).
// Elementwise fully in-register (gate z via one shfl_xor(32); no LDS scratch).
__global__ void __launch_bounds__(TBLK, 1)
gru_main(const float* __restrict__ x,
         const float* __restrict__ wih0, const float* __restrict__ whh0,
         const float* __restrict__ bi0,  const float* __restrict__ bh0,
         const float* __restrict__ wih1, const float* __restrict__ whh1,
         const float* __restrict__ bi1,  const float* __restrict__ bh1,
         const float* __restrict__ fcb,  const float* __restrict__ fcT,
         ushort_t* xpack, ushort_t* h0pack, ushort_t* h1pack,
         unsigned* flags,
         float* __restrict__ out)
{
    extern __shared__ char smem_raw[];
    __shared__ unsigned s_bc;
    ushort_t* whi = (ushort_t*)smem_raw;            // 32768 ush (64 KB)
    ushort_t* wlo = whi + WHI_USH;                  // 64 KB

    const int bid = blockIdx.x, tid = threadIdx.x;
    const int L  = bid >> 7;
    const int UG = (bid >> 1) & 63;      // 8-unit group
    const int CT = bid & 1;              // col half (128 batches)
    const int wid = tid >> 6, lane = tid & 63;

    // ---- stage this block's weights into LDS (hi+lo planes, A-frag layout) ----
    {
        const float* Wgi = L ? wih1 : wih0;
        const float* Wgh = L ? whh1 : whh0;
        const int Kgi = L ? HH : NS;
        for (int idx = tid; idx < 32768; idx += TBLK) {
            const int j = idx & 7, ln = (idx >> 3) & 63, rc = idx >> 9;  // rc = wc*2+rt
            const int c = rc >> 1, rt = rc & 1;
            const int m = ln & 15, qq = ln >> 4;
            const int lr = rt * 16 + m;          // 0..31 (rows 24..31 pad)
            const int g = lr >> 3, u = lr & 7;
            float v = 0.f;
            if (g < 3) {
                if (c < 16) {
                    const int k = c * 32 + qq * 8 + j;
                    if (k < Kgi) v = Wgi[(size_t)(g * HH + UG * 8 + u) * Kgi + k];
                } else {
                    const int k = (c - 16) * 32 + qq * 8 + j;
                    v = Wgh[(size_t)(g * HH + UG * 8 + u) * HH + k];
                }
            }
            const ushort_t hb = f2bf(v);
            whi[idx] = hb;
            wlo[idx] = f2bf(v - bf2f(hb));
        }
    }

    // ---- per-XCD membership discovery (dispatch-mapping independent) ----
    int myxcd;
    asm volatile("s_getreg_b32 %0, hwreg(HW_REG_XCC_ID)" : "=s"(myxcd));
    myxcd &= 7;
    unsigned* xcnt = flags + 12288;
    unsigned* xmem = flags + 16384;
    if (tid == 0) {
        unsigned slot = atomicAdd(xcnt + ((size_t)myxcd << 4), 1u);
        if (slot < 64) st_flag(xmem + myxcd * 64 + slot, (unsigned)bid);
        asm volatile("s_waitcnt vmcnt(0)" ::: "memory");
        s_bc = slot;
    }
    __syncthreads();
    const bool isLead = (s_bc == 0);
    __syncthreads();

    // init flat barrier (phase 1): membership globally visible after this
    dbar_flat(flags, 1, bid);

    unsigned cnt = 0, mymem = 0;
    bool wact = false;
    if (isLead) {
        cnt = ld_flag(xcnt + ((size_t)myxcd << 4));
        if (cnt > 64) cnt = 64;
        if (tid < cnt) mymem = ld_flag(xmem + myxcd * 64 + tid);
        if (tid < 8) wact = (ld_flag(xcnt + ((size_t)tid << 4)) > 0);
    }

    // per-lane unit base for elementwise: lanes q in {0,1} own units ub..ub+3
    const int ub = ((lane >> 4) & 1) * 4;
    float biR[4], biZ[4], biN[4], bhR[4], bhZ[4], bhN[4];
    {
        const float* bi = L ? bi1 : bi0;
        const float* bh = L ? bh1 : bh0;
#pragma unroll
        for (int p = 0; p < 4; ++p) {
            const int ugl = UG * 8 + ub + p;
            biR[p] = bi[ugl]; biZ[p] = bi[HH + ugl]; biN[p] = bi[2 * HH + ugl];
            bhR[p] = bh[ugl]; bhZ[p] = bh[HH + ugl]; bhN[p] = bh[2 * HH + ugl];
        }
    }
    float hreg[2][4] = {{0.f, 0.f, 0.f, 0.f}, {0.f, 0.f, 0.f, 0.f}};  // [t][r4]
    const int chW = UG >> 2, qqW = UG & 3;  // pack-write constants
    __syncthreads();

    const ushort_t* whiS = whi + (size_t)lane * 8;
    const ushort_t* wloS = wlo + (size_t)lane * 8;
    const size_t apoff = ((size_t)(CT * 8 + wid * 2) * 64 + lane) * 8;

    for (int s = 0; s <= TT; ++s) {
        const unsigned phase = (unsigned)s + 2;
        const bool active = L ? (s >= 1) : (s < TT);
        if (active) {
            const ushort_t *gisrc, *ghsrc;
            if (L == 0) {
                gisrc = xpack + (size_t)(s & 1) * 2 * PL_USH;
                ghsrc = h0pack + (size_t)((s - 1) & 1) * 2 * PL_USH;
            } else {
                gisrc = h0pack + (size_t)((s - 1) & 1) * 2 * PL_USH;
                ghsrc = h1pack + (size_t)(s & 1) * 2 * PL_USH;
            }
            floatx4 z4 = {0.f, 0.f, 0.f, 0.f};
            floatx4 aGI[2][2], aGH[2][2];
#pragma unroll
            for (int i = 0; i < 2; ++i) { aGI[i][0] = z4; aGI[i][1] = z4; aGH[i][0] = z4; aGH[i][1] = z4; }
            gemm_both(gisrc + apoff, ghsrc + apoff, whiS, wloS, aGI, aGH);

            // ---- x staging loads for step s+1 (issue early, store later) ----
            float4 xv0, xv1;
            const bool doX = (s <= TT - 2) && (bid * TBLK + tid < 16384);
            int xko = 0, xb = 0;
            if (doX) {
                const int gx = bid * TBLK + tid;
                xko = gx & 63; xb = gx >> 6;
                const float* xs = x + ((size_t)xb * TT + (s + 1)) * NS + xko * 8;
                if (xko < 62) { xv0 = *(const float4*)(xs); xv1 = *(const float4*)(xs + 4); }
                else {
                    float tmp[8];
#pragma unroll
                    for (int j = 0; j < 8; ++j) {
                        const int k = xko * 8 + j;
                        tmp[j] = (k < NS) ? xs[j] : 0.f;
                    }
                    xv0 = make_float4(tmp[0], tmp[1], tmp[2], tmp[3]);
                    xv1 = make_float4(tmp[4], tmp[5], tmp[6], tmp[7]);
                }
            }

            // ---- in-register elementwise (no LDS, no syncs) ----
            float zGI[2][4], zGH[2][4];
#pragma unroll
            for (int t = 0; t < 2; ++t)
#pragma unroll
                for (int r = 0; r < 4; ++r) {
                    zGI[t][r] = __shfl_xor(aGI[0][t][r], 32, 64);
                    zGH[t][r] = __shfl_xor(aGH[0][t][r], 32, 64);
                }
            ushort_t* pk = L ? h1pack + (size_t)((s - 1) & 1) * 2 * PL_USH
                             : h0pack + (size_t)(s & 1) * 2 * PL_USH;
            if (lane < 32) {
#pragma unroll
                for (int t = 0; t < 2; ++t) {
                    ushort_t hi4[4], lo4[4];
#pragma unroll
                    for (int r = 0; r < 4; ++r) {
                        const float gir = aGI[0][t][r], ghr = aGH[0][t][r];
                        const float giz = zGI[t][r],    ghz = zGH[t][r];
                        const float gin = aGI[1][t][r], ghn = aGH[1][t][r];
                        const float rr = sigm(gir + biR[r] + ghr + bhR[r]);
                        const float zz = sigm(giz + biZ[r] + ghz + bhZ[r]);
                        const float nn = tanhf(gin + biN[r] + rr * (ghn + bhN[r]));
                        const float hv = (1.f - zz) * nn + zz * hreg[t][r];
                        hreg[t][r] = hv;
                        hi4[r] = f2bf(hv);
                        lo4[r] = f2bf(hv - bf2f(hi4[r]));
                    }
                    const int b = CT * 128 + wid * 32 + t * 16 + (lane & 15);
                    const size_t o8 = ((size_t)(chW * 16 + (b >> 4)) * 64 + qqW * 16 + (b & 15)) * 8 + ub;
                    *(u64*)(pk + o8) = pack4(hi4);            // plain write-back stores
                    *(u64*)(pk + PL_USH + o8) = pack4(lo4);
                }
            }

            // ---- x staging stores (plain write-back) ----
            if (doX) {
                ushort_t hi8[8], lo8[8];
                float vv[8] = {xv0.x, xv0.y, xv0.z, xv0.w, xv1.x, xv1.y, xv1.z, xv1.w};
#pragma unroll
                for (int j = 0; j < 8; ++j) {
                    hi8[j] = f2bf(vv[j]);
                    lo8[j] = f2bf(vv[j] - bf2f(hi8[j]));
                }
                ushort_t* xp = xpack + (size_t)((s + 1) & 1) * 2 * PL_USH;
                const size_t o = ((size_t)((xko >> 2) * 16 + (xb >> 4)) * 64 + (xko & 3) * 16 + (xb & 15)) * 8;
                *(uint4*)(xp + o) = *(uint4*)hi8;
                *(uint4*)(xp + PL_USH + o) = *(uint4*)lo8;
            }
        } else if ((s <= TT - 2) && (bid * TBLK + tid < 16384)) {
            // inactive blocks still stage x
            const int gx = bid * TBLK + tid;
            const int xko = gx & 63, xb = gx >> 6;
            const float* xs = x + ((size_t)xb * TT + (s + 1)) * NS + xko * 8;
            ushort_t hi8[8], lo8[8];
#pragma unroll
            for (int j = 0; j < 8; ++j) {
                const int k = xko * 8 + j;
                const float v = (k < NS) ? xs[j] : 0.f;
                hi8[j] = f2bf(v);
                lo8[j] = f2bf(v - bf2f(hi8[j]));
            }
            ushort_t* xp = xpack + (size_t)((s + 1) & 1) * 2 * PL_USH;
            const size_t o = ((size_t)((xko >> 2) * 16 + (xb >> 4)) * 64 + (xko & 3) * 16 + (xb & 15)) * 8;
            *(uint4*)(xp + o) = *(uint4*)hi8;
            *(uint4*)(xp + PL_USH + o) = *(uint4*)lo8;
        }
        dbar2(flags, phase, bid, myxcd, isLead, cnt, mymem, wact);
    }

    // ================= epilogue: FC + silu + softmax + rebalance (block = batch) =========
    {
        const int b = bid;
        float* sh = (float*)smem_raw;       // 512 floats (weights region, now dead)
        float* scr = sh + 576;
        const ushort_t* pk = h1pack + (size_t)1 * 2 * PL_USH;   // h1[249], parity 1
        for (int u = tid; u < HH; u += TBLK) {
            const int uo = u >> 3, j = u & 7;
            const size_t o = ((size_t)((uo >> 2) * 16 + (b >> 4)) * 64 + (uo & 3) * 16 + (b & 15)) * 8 + j;
            sh[u] = bf2f(pk[o]) + bf2f(pk[PL_USH + o]);
        }
        __syncthreads();

        const int o1 = tid;
        const bool v2 = (tid + 256) < NS;
        const int o2 = v2 ? (tid + 256) : (NS - 1);
        float a0 = fcb[o1], a1 = fcb[o2];
        for (int k = 0; k < HH; ++k) {
            const float hv = sh[k];
            const float* fr = fcT + (size_t)k * NS;
            a0 = fmaf(hv, fr[o1], a0);
            a1 = fmaf(hv, fr[o2], a1);
        }
        float l0 = a0 * sigm(a0);
        float l1 = a1 * sigm(a1);
        float mx = block_max4(fmaxf(l0, v2 ? l1 : -3.4e38f), scr);
        float e0 = expf(l0 - mx);
        float e1 = v2 ? expf(l1 - mx) : 0.f;
        float2 s2 = block_sum2_4(e0 + e1, 0.f, scr);
        float w0 = e0 / s2.x, w1 = e1 / s2.x;
        for (int it = 0; it < 30; ++it) {
            float c0v = fminf(fmaxf(w0, 0.f), 0.1f);
            float c1v = fminf(fmaxf(w1, 0.f), 0.1f);
            float lv = (w0 - c0v) + (w1 - c1v);
            float n0 = (c0v != 0.1f) ? c0v : 0.f;
            float n1 = (v2 && c1v != 0.1f) ? c1v : 0.f;
            float2 rs = block_sum2_4(lv, n0 + n1, scr);
            float inv = rs.x / rs.y;
            w0 = c0v + inv * n0;
            w1 = c1v + inv * n1;
        }
        out[(size_t)b * NS + o1] = w0;
        if (v2) out[(size_t)b * NS + tid + 256] = w1;
    }
}

// ---------------- prep: pack x[t=0] ----------------
__global__ void pack_x0(const float* __restrict__ x, ushort_t* __restrict__ xpack) {
    const int t = blockIdx.x * 256 + threadIdx.x;   // 16384 threads
    const int ko = t & 63, b = t >> 6;
    const float* xs = x + (size_t)b * TT * NS;      // t=0
    ushort_t hi8[8], lo8[8];
#pragma unroll
    for (int j = 0; j < 8; ++j) {
        const int k = ko * 8 + j;
        const float v = (k < NS) ? xs[k] : 0.f;
        hi8[j] = f2bf(v);
        lo8[j] = f2bf(v - bf2f(hi8[j]));
    }
    const size_t o = ((size_t)((ko >> 2) * 16 + (b >> 4)) * 64 + (ko & 3) * 16 + (b & 15)) * 8;
    *(uint4*)(xpack + o) = *(uint4*)hi8;
    *(uint4*)(xpack + PL_USH + o) = *(uint4*)lo8;
}

// ---------------- prep: fc weight transpose ----------------
__global__ void transpose_k(const float* __restrict__ src, float* __restrict__ dst,
                            int G, int K) {
    int idx = blockIdx.x * 256 + threadIdx.x;
    if (idx >= G * K) return;
    int k = idx / G, g = idx - k * G;
    dst[idx] = src[(size_t)g * K + k];
}

// ---------------- launch ----------------
extern "C" void kernel_launch(void* const* d_in, const int* in_sizes, int n_in,
                              void* d_out, int out_size, void* d_ws, size_t ws_size,
                              hipStream_t stream) {
    const float* x    = (const float*)d_in[0];
    const float* wih0 = (const float*)d_in[1];
    const float* whh0 = (const float*)d_in[2];
    const float* bih0 = (const float*)d_in[3];
    const float* bhh0 = (const float*)d_in[4];
    const float* wih1 = (const float*)d_in[5];
    const float* whh1 = (const float*)d_in[6];
    const float* bih1 = (const float*)d_in[7];
    const float* bhh1 = (const float*)d_in[8];
    const float* fcw  = (const float*)d_in[9];
    const float* fcb  = (const float*)d_in[10];
    float* outp = (float*)d_out;

    // ws layout (~4.4 MB):
    char* ws = (char*)d_ws;
    unsigned* flags  = (unsigned*)ws;                         // arrival+wb/inv+cnt+members in 196608
    ushort_t* h0pack = (ushort_t*)(ws + 196608);              // 1 MB
    ushort_t* h1pack = (ushort_t*)(ws + 196608 + 1048576);    // 1 MB
    ushort_t* xpack  = (ushort_t*)(ws + 196608 + 2097152);    // 1 MB
    float*    fcT    = (float*)(ws + 196608 + 3145728);       // 512*500*4 = 1024000

    // zero: flags + h packs (h0 = 0 both parities)
    hipMemsetAsync(ws, 0, 196608 + 2097152, stream);
    pack_x0<<<64, 256, 0, stream>>>(x, xpack);
    {
        int nel = NS * HH;
        transpose_k<<<(nel + 255) / 256, 256, 0, stream>>>(fcw, fcT, NS, HH);
    }

    hipFuncSetAttribute((const void*)gru_main,
                        hipFuncAttributeMaxDynamicSharedMemorySize, SMEMB);

    void* args[] = {(void*)&x,
                    (void*)&wih0, (void*)&whh0, (void*)&bih0, (void*)&bhh0,
                    (void*)&wih1, (void*)&whh1, (void*)&bih1, (void*)&bhh1,
                    (void*)&fcb, (void*)&fcT,
                    (void*)&xpack, (void*)&h0pack, (void*)&h1pack,
                    (void*)&flags, (void*)&outp};
    hipError_t e = hipLaunchCooperativeKernel((const void*)gru_main, dim3(NBLK), dim3(TBLK),
                                              args, SMEMB, stream);
    if (e != hipSuccess) {
        gru_main<<<dim3(NBLK), dim3(TBLK), SMEMB, stream>>>(
            x, wih0, whh0, bih0, bhh0, wih1, whh1, bih1, bhh1,
            fcb, fcT, xpack, h0pack, h1pack, flags, outp);
    }
}

// Round 7
// 3326.820 us; speedup vs baseline: 1.7355x; 1.7355x over previous
//
#include <hip/hip_runtime.h>
#include <math.h>

typedef __attribute__((ext_vector_type(8))) short short8;
typedef __attribute__((ext_vector_type(4))) float floatx4;
typedef unsigned short ushort_t;
typedef unsigned int uint32;
typedef unsigned long long u64;

#define BB 256
#define TT 250
#define NS 500
#define HH 512
#define NBLK 256
#define TBLK 512
#define PL_USH 131072u      // act plane: 16ch*16ct*64lane*8 ushorts (512K x 256 bf16)
#define CH_USH 8192u        // act chunk stride: 16ct*64*8
#define WHI_USH 32768
#define SMEMB 131072        // weights hi+lo only; epilogue reuses the same region

// ---- bf16 split helpers (RNE) ----
__device__ __forceinline__ ushort_t f2bf(float f) {
    uint32 u = __float_as_uint(f);
    u += 0x7fffu + ((u >> 16) & 1u);
    return (ushort_t)(u >> 16);
}
__device__ __forceinline__ float bf2f(ushort_t h) { return __uint_as_float(((uint32)h) << 16); }
__device__ __forceinline__ float sigm(float x) { return 1.f / (1.f + expf(-x)); }
__device__ __forceinline__ floatx4 mfma16(short8 a, short8 b, floatx4 c) {
    return __builtin_amdgcn_mfma_f32_16x16x32_bf16(a, b, c, 0, 0, 0);
}
__device__ __forceinline__ u64 pack4(const ushort_t* a) {
    return (u64)a[0] | ((u64)a[1] << 16) | ((u64)a[2] << 32) | ((u64)a[3] << 48);
}
__device__ __forceinline__ void st_agent_u64(ushort_t* p, u64 v) {
    __hip_atomic_store((u64*)p, v, __ATOMIC_RELAXED, __HIP_MEMORY_SCOPE_AGENT);
}
__device__ __forceinline__ void st_agent_u64x(uint4* p, uint4 v) {
    u64* q = (u64*)p;
    __hip_atomic_store(q,     (u64)v.x | ((u64)v.y << 32), __ATOMIC_RELAXED, __HIP_MEMORY_SCOPE_AGENT);
    __hip_atomic_store(q + 1, (u64)v.z | ((u64)v.w << 32), __ATOMIC_RELAXED, __HIP_MEMORY_SCOPE_AGENT);
}

// ------------- flat one-round barrier: thread j polls block j's flag ------------------
// Cross-block data is written sc1 (write-through L3) and read sc0+sc1 (L1/L2-bypass) so
// no cache maintenance is ever needed (R6 proved maintenance costs more than it saves).
__device__ __forceinline__ void dbar(unsigned* flags, unsigned phase, int bid) {
    __syncthreads();   // drains this block's pack stores (vmcnt(0) before s_barrier)
    if (threadIdx.x == 0)
        __hip_atomic_store(flags + ((size_t)bid << 4), phase,
                           __ATOMIC_RELAXED, __HIP_MEMORY_SCOPE_AGENT);
    if (threadIdx.x < NBLK) {
        unsigned* sp = flags + ((size_t)threadIdx.x << 4);
        while (__hip_atomic_load(sp, __ATOMIC_RELAXED, __HIP_MEMORY_SCOPE_AGENT) < phase)
            __builtin_amdgcn_s_sleep(2);
    }
    __syncthreads();
}

// ---------------- block reductions (512 thr = 8 waves) ----------------
__device__ __forceinline__ float block_max8(float v, float* scr) {
#pragma unroll
    for (int off = 32; off; off >>= 1) v = fmaxf(v, __shfl_down(v, off, 64));
    if ((threadIdx.x & 63) == 0) scr[threadIdx.x >> 6] = v;
    __syncthreads();
    if (threadIdx.x == 0) {
        float m = scr[0];
#pragma unroll
        for (int w = 1; w < 8; ++w) m = fmaxf(m, scr[w]);
        scr[16] = m;
    }
    __syncthreads();
    float r = scr[16];
    __syncthreads();
    return r;
}
__device__ __forceinline__ float2 block_sum2_8(float a, float b, float* scr) {
#pragma unroll
    for (int off = 32; off; off >>= 1) {
        a += __shfl_down(a, off, 64);
        b += __shfl_down(b, off, 64);
    }
    if ((threadIdx.x & 63) == 0) { int w = threadIdx.x >> 6; scr[w] = a; scr[8 + w] = b; }
    __syncthreads();
    if (threadIdx.x == 0) {
        float sa = 0.f, sb = 0.f;
#pragma unroll
        for (int w = 0; w < 8; ++w) { sa += scr[w]; sb += scr[8 + w]; }
        scr[16] = sa; scr[17] = sb;
    }
    __syncthreads();
    float2 r = make_float2(scr[16], scr[17]);
    __syncthreads();
    return r;
}

// ------------- fused gi+gh GEMM: 32 chunks of K=32, ONE col-tile per wave --------------
// Hand-held pipeline: asm global_load_dwordx4 (sc0 sc1 = L1/L2-bypass, L3-fresh) into a
// 12-slot ring (depth 11 = 22 loads in flight), counted s_waitcnt vmcnt(N) +
// sched_barrier before each chunk's 6 MFMAs. Weights double-buffered one chunk ahead.
__device__ __forceinline__ void gemm_both(const ushort_t* __restrict__ gp,
                                          const ushort_t* __restrict__ hp,
                                          const ushort_t* whiS, const ushort_t* wloS,
                                          floatx4 (&aGI)[2], floatx4 (&aGH)[2]) {
    short8 Bh[12], Bl[12];
    const ushort_t* gpl = gp + PL_USH;
    const ushort_t* hpl = hp + PL_USH;

#define ISSUE(pc) do {                                                                    \
        const ushort_t* _ph = ((pc) < 16) ? (gp + (size_t)(pc) * CH_USH)                  \
                                          : (hp + (size_t)((pc) - 16) * CH_USH);          \
        const ushort_t* _pl = ((pc) < 16) ? (gpl + (size_t)(pc) * CH_USH)                 \
                                          : (hpl + (size_t)((pc) - 16) * CH_USH);         \
        asm volatile("global_load_dwordx4 %0, %1, off sc0 sc1"                            \
                     : "=v"(Bh[(pc) % 12]) : "v"(_ph));                                   \
        asm volatile("global_load_dwordx4 %0, %1, off sc0 sc1"                            \
                     : "=v"(Bl[(pc) % 12]) : "v"(_pl));                                   \
    } while (0)

    ISSUE(0); ISSUE(1); ISSUE(2); ISSUE(3); ISSUE(4); ISSUE(5);
    ISSUE(6); ISSUE(7); ISSUE(8); ISSUE(9); ISSUE(10);

    short8 w0h = *(const short8*)(whiS);
    short8 w1h = *(const short8*)(whiS + 512);
    short8 w0l = *(const short8*)(wloS);
    short8 w1l = *(const short8*)(wloS + 512);

#define GSTEP(c, N) do {                                                                  \
        if ((c) + 11 < 32) ISSUE((c) + 11);                                               \
        short8 n0h, n1h, n0l, n1l;                                                        \
        if ((c) + 1 < 32) {                                                               \
            const size_t _w = (size_t)(((c) + 1) * 2) * 512;                              \
            n0h = *(const short8*)(whiS + _w);                                            \
            n1h = *(const short8*)(whiS + _w + 512);                                      \
            n0l = *(const short8*)(wloS + _w);                                            \
            n1l = *(const short8*)(wloS + _w + 512);                                      \
        }                                                                                 \
        asm volatile("s_waitcnt vmcnt(" #N ")" ::: "memory");                             \
        __builtin_amdgcn_sched_barrier(0);                                                \
        const int _cs = (c) % 12;                                                         \
        floatx4 (&A)[2] = ((c) < 16) ? aGI : aGH;                                         \
        A[0] = mfma16(w0h, Bh[_cs], A[0]);                                                \
        A[1] = mfma16(w1h, Bh[_cs], A[1]);                                                \
        A[0] = mfma16(w0h, Bl[_cs], A[0]);                                                \
        A[1] = mfma16(w1h, Bl[_cs], A[1]);                                                \
        A[0] = mfma16(w0l, Bh[_cs], A[0]);                                                \
        A[1] = mfma16(w1l, Bh[_cs], A[1]);                                                \
        if ((c) + 1 < 32) { w0h = n0h; w1h = n1h; w0l = n0l; w1l = n1l; }                 \
    } while (0)

    GSTEP(0, 22);  GSTEP(1, 22);  GSTEP(2, 22);  GSTEP(3, 22);  GSTEP(4, 22);
    GSTEP(5, 22);  GSTEP(6, 22);  GSTEP(7, 22);  GSTEP(8, 22);  GSTEP(9, 22);
    GSTEP(10, 22); GSTEP(11, 22); GSTEP(12, 22); GSTEP(13, 22); GSTEP(14, 22);
    GSTEP(15, 22); GSTEP(16, 22); GSTEP(17, 22); GSTEP(18, 22); GSTEP(19, 22);
    GSTEP(20, 22); GSTEP(21, 20); GSTEP(22, 18); GSTEP(23, 16); GSTEP(24, 14);
    GSTEP(25, 12); GSTEP(26, 10); GSTEP(27, 8);  GSTEP(28, 6);  GSTEP(29, 4);
    GSTEP(30, 2);  GSTEP(31, 0);
#undef GSTEP
#undef ISSUE
}

// ---------------- main persistent kernel ----------------
// 256 blocks x 512 threads (8 waves = 2 waves/SIMD for latency hiding).
// Block = L(2) x UG(64 groups of 8 units) x CT(2 col-halves of 128 batches).
// Wave wid owns ONE 16-batch col-tile (ct = CT*8 + wid). Elementwise fully in-register.
__global__ void __launch_bounds__(TBLK, 2)
gru_main(const float* __restrict__ x,
         const float* __restrict__ wih0, const float* __restrict__ whh0,
         const float* __restrict__ bi0,  const float* __restrict__ bh0,
         const float* __restrict__ wih1, const float* __restrict__ whh1,
         const float* __restrict__ bi1,  const float* __restrict__ bh1,
         const float* __restrict__ fcb,  const float* __restrict__ fcT,
         ushort_t* xpack, ushort_t* h0pack, ushort_t* h1pack,
         unsigned* flags,
         float* __restrict__ out)
{
    extern __shared__ char smem_raw[];
    ushort_t* whi = (ushort_t*)smem_raw;            // 32768 ush (64 KB)
    ushort_t* wlo = whi + WHI_USH;                  // 64 KB

    const int bid = blockIdx.x, tid = threadIdx.x;
    const int L  = bid >> 7;
    const int UG = (bid >> 1) & 63;      // 8-unit group
    const int CT = bid & 1;              // col half (128 batches)
    const int wid = tid >> 6, lane = tid & 63;

    // ---- stage this block's weights into LDS (hi+lo planes, A-frag layout) ----
    {
        const float* Wgi = L ? wih1 : wih0;
        const float* Wgh = L ? whh1 : whh0;
        const int Kgi = L ? HH : NS;
        for (int idx = tid; idx < 32768; idx += TBLK) {
            const int j = idx & 7, ln = (idx >> 3) & 63, rc = idx >> 9;  // rc = c*2+rt
            const int c = rc >> 1, rt = rc & 1;
            const int m = ln & 15, qq = ln >> 4;
            const int lr = rt * 16 + m;          // 0..31 (rows 24..31 pad)
            const int g = lr >> 3, u = lr & 7;
            float v = 0.f;
            if (g < 3) {
                if (c < 16) {
                    const int k = c * 32 + qq * 8 + j;
                    if (k < Kgi) v = Wgi[(size_t)(g * HH + UG * 8 + u) * Kgi + k];
                } else {
                    const int k = (c - 16) * 32 + qq * 8 + j;
                    v = Wgh[(size_t)(g * HH + UG * 8 + u) * HH + k];
                }
            }
            const ushort_t hb = f2bf(v);
            whi[idx] = hb;
            wlo[idx] = f2bf(v - bf2f(hb));
        }
    }

    // per-lane unit base for elementwise: lanes 0-15 units 0-3, lanes 16-31 units 4-7
    const int ub = ((lane >> 4) & 1) * 4;
    float biR[4], biZ[4], biN[4], bhR[4], bhZ[4], bhN[4];
    {
        const float* bi = L ? bi1 : bi0;
        const float* bh = L ? bh1 : bh0;
#pragma unroll
        for (int p = 0; p < 4; ++p) {
            const int ugl = UG * 8 + ub + p;
            biR[p] = bi[ugl]; biZ[p] = bi[HH + ugl]; biN[p] = bi[2 * HH + ugl];
            bhR[p] = bh[ugl]; bhZ[p] = bh[HH + ugl]; bhN[p] = bh[2 * HH + ugl];
        }
    }
    float hreg[4] = {0.f, 0.f, 0.f, 0.f};   // [r4] for this wave's 16-batch tile
    const int chW = UG >> 2, qqW = UG & 3;  // pack-write constants
    __syncthreads();

    const ushort_t* whiS = whi + (size_t)lane * 8;
    const ushort_t* wloS = wlo + (size_t)lane * 8;
    const size_t apoff = ((size_t)(CT * 8 + wid) * 64 + lane) * 8;

    for (int s = 0; s <= TT; ++s) {
        const unsigned phase = (unsigned)s + 1;
        const bool active = L ? (s >= 1) : (s < TT);
        if (active) {
            const ushort_t *gisrc, *ghsrc;
            if (L == 0) {
                gisrc = xpack + (size_t)(s & 1) * 2 * PL_USH;
                ghsrc = h0pack + (size_t)((s - 1) & 1) * 2 * PL_USH;
            } else {
                gisrc = h0pack + (size_t)((s - 1) & 1) * 2 * PL_USH;
                ghsrc = h1pack + (size_t)(s & 1) * 2 * PL_USH;
            }
            floatx4 z4 = {0.f, 0.f, 0.f, 0.f};
            floatx4 aGI[2], aGH[2];
            aGI[0] = z4; aGI[1] = z4; aGH[0] = z4; aGH[1] = z4;
            gemm_both(gisrc + apoff, ghsrc + apoff, whiS, wloS, aGI, aGH);

            // ---- x staging loads for step s+1 (issue early, store later) ----
            float4 xv0, xv1;
            const bool doX = (s <= TT - 2) && (bid * TBLK + tid < 16384);
            int xko = 0, xb = 0;
            if (doX) {
                const int gx = bid * TBLK + tid;
                xko = gx & 63; xb = gx >> 6;
                const float* xs = x + ((size_t)xb * TT + (s + 1)) * NS + xko * 8;
                if (xko < 62) { xv0 = *(const float4*)(xs); xv1 = *(const float4*)(xs + 4); }
                else {
                    float tmp[8];
#pragma unroll
                    for (int j = 0; j < 8; ++j) {
                        const int k = xko * 8 + j;
                        tmp[j] = (k < NS) ? xs[j] : 0.f;
                    }
                    xv0 = make_float4(tmp[0], tmp[1], tmp[2], tmp[3]);
                    xv1 = make_float4(tmp[4], tmp[5], tmp[6], tmp[7]);
                }
            }

            // ---- in-register elementwise (no LDS, no syncs) ----
            // gate r: aGI[0] rows 0-7 (lanes<32); gate z: rows 8-15 = lane+32;
            // gate n: aGI[1] rows 16-23 (lanes<32).
            float zGI[4], zGH[4];
#pragma unroll
            for (int r = 0; r < 4; ++r) {
                zGI[r] = __shfl_xor(aGI[0][r], 32, 64);
                zGH[r] = __shfl_xor(aGH[0][r], 32, 64);
            }
            ushort_t* pk = L ? h1pack + (size_t)((s - 1) & 1) * 2 * PL_USH
                             : h0pack + (size_t)(s & 1) * 2 * PL_USH;
            if (lane < 32) {
                ushort_t hi4[4], lo4[4];
#pragma unroll
                for (int r = 0; r < 4; ++r) {
                    const float gir = aGI[0][r], ghr = aGH[0][r];
                    const float giz = zGI[r],    ghz = zGH[r];
                    const float gin = aGI[1][r], ghn = aGH[1][r];
                    const float rr = sigm(gir + biR[r] + ghr + bhR[r]);
                    const float zz = sigm(giz + biZ[r] + ghz + bhZ[r]);
                    const float nn = tanhf(gin + biN[r] + rr * (ghn + bhN[r]));
                    const float hv = (1.f - zz) * nn + zz * hreg[r];
                    hreg[r] = hv;
                    hi4[r] = f2bf(hv);
                    lo4[r] = f2bf(hv - bf2f(hi4[r]));
                }
                const int b = CT * 128 + wid * 16 + (lane & 15);
                const size_t o8 = ((size_t)(chW * 16 + (b >> 4)) * 64 + qqW * 16 + (b & 15)) * 8 + ub;
                st_agent_u64(pk + o8, pack4(hi4));
                st_agent_u64(pk + PL_USH + o8, pack4(lo4));
            }

            // ---- x staging stores (write-through) ----
            if (doX) {
                ushort_t hi8[8], lo8[8];
                float vv[8] = {xv0.x, xv0.y, xv0.z, xv0.w, xv1.x, xv1.y, xv1.z, xv1.w};
#pragma unroll
                for (int j = 0; j < 8; ++j) {
                    hi8[j] = f2bf(vv[j]);
                    lo8[j] = f2bf(vv[j] - bf2f(hi8[j]));
                }
                ushort_t* xp = xpack + (size_t)((s + 1) & 1) * 2 * PL_USH;
                const size_t o = ((size_t)((xko >> 2) * 16 + (xb >> 4)) * 64 + (xko & 3) * 16 + (xb & 15)) * 8;
                st_agent_u64(xp + o, pack4(hi8));
                st_agent_u64(xp + o + 4, pack4(hi8 + 4));
                st_agent_u64(xp + PL_USH + o, pack4(lo8));
                st_agent_u64(xp + PL_USH + o + 4, pack4(lo8 + 4));
            }
        } else if ((s <= TT - 2) && (bid * TBLK + tid < 16384)) {
            // inactive blocks still stage x (dead for this mapping, kept for safety)
            const int gx = bid * TBLK + tid;
            const int xko = gx & 63, xb = gx >> 6;
            const float* xs = x + ((size_t)xb * TT + (s + 1)) * NS + xko * 8;
            ushort_t hi8[8], lo8[8];
#pragma unroll
            for (int j = 0; j < 8; ++j) {
                const int k = xko * 8 + j;
                const float v = (k < NS) ? xs[j] : 0.f;
                hi8[j] = f2bf(v);
                lo8[j] = f2bf(v - bf2f(hi8[j]));
            }
            ushort_t* xp = xpack + (size_t)((s + 1) & 1) * 2 * PL_USH;
            const size_t o = ((size_t)((xko >> 2) * 16 + (xb >> 4)) * 64 + (xko & 3) * 16 + (xb & 15)) * 8;
            st_agent_u64(xp + o, pack4(hi8));
            st_agent_u64(xp + o + 4, pack4(hi8 + 4));
            st_agent_u64(xp + PL_USH + o, pack4(lo8));
            st_agent_u64(xp + PL_USH + o + 4, pack4(lo8 + 4));
        }
        dbar(flags, phase, bid);
    }

    // ================= epilogue: FC + silu + softmax + rebalance (block = batch) =========
    {
        const int b = bid;
        float* sh = (float*)smem_raw;       // 512 floats (weights region, now dead)
        float* scr = sh + 512;              // 32 floats scratch
        const ushort_t* pk = h1pack + (size_t)1 * 2 * PL_USH;   // h1[249], parity 1
        {
            const int u = tid;              // 512 threads <-> 512 units
            const int uo = u >> 3, j = u & 7;
            const size_t o = ((size_t)((uo >> 2) * 16 + (b >> 4)) * 64 + (uo & 3) * 16 + (b & 15)) * 8 + j;
            sh[u] = bf2f(pk[o]) + bf2f(pk[PL_USH + o]);
        }
        __syncthreads();

        const bool valid = tid < NS;
        const int o1 = valid ? tid : 0;
        float a0 = fcb[o1];
        for (int k = 0; k < HH; ++k)
            a0 = fmaf(sh[k], fcT[(size_t)k * NS + o1], a0);
        float l0 = a0 * sigm(a0);
        float mx = block_max8(valid ? l0 : -3.4e38f, scr);
        float e0 = valid ? expf(l0 - mx) : 0.f;
        float2 s2 = block_sum2_8(e0, 0.f, scr);
        float w0 = e0 / s2.x;
        for (int it = 0; it < 30; ++it) {
            float c0v = fminf(fmaxf(w0, 0.f), 0.1f);
            float lv = w0 - c0v;
            float n0 = (c0v != 0.1f) ? c0v : 0.f;   // invalid threads: c0v=0 -> n0=0
            float2 rs = block_sum2_8(lv, n0, scr);
            w0 = c0v + rs.x / rs.y * n0;
        }
        if (valid) out[(size_t)b * NS + tid] = w0;
    }
}

// ---------------- prep: pack x[t=0] ----------------
__global__ void pack_x0(const float* __restrict__ x, ushort_t* __restrict__ xpack) {
    const int t = blockIdx.x * 256 + threadIdx.x;   // 16384 threads
    const int ko = t & 63, b = t >> 6;
    const float* xs = x + (size_t)b * TT * NS;      // t=0
    ushort_t hi8[8], lo8[8];
#pragma unroll
    for (int j = 0; j < 8; ++j) {
        const int k = ko * 8 + j;
        const float v = (k < NS) ? xs[k] : 0.f;
        hi8[j] = f2bf(v);
        lo8[j] = f2bf(v - bf2f(hi8[j]));
    }
    const size_t o = ((size_t)((ko >> 2) * 16 + (b >> 4)) * 64 + (ko & 3) * 16 + (b & 15)) * 8;
    *(uint4*)(xpack + o) = *(uint4*)hi8;
    *(uint4*)(xpack + PL_USH + o) = *(uint4*)lo8;
}

// ---------------- prep: fc weight transpose ----------------
__global__ void transpose_k(const float* __restrict__ src, float* __restrict__ dst,
                            int G, int K) {
    int idx = blockIdx.x * 256 + threadIdx.x;
    if (idx >= G * K) return;
    int k = idx / G, g = idx - k * G;
    dst[idx] = src[(size_t)g * K + k];
}

// ---------------- launch ----------------
extern "C" void kernel_launch(void* const* d_in, const int* in_sizes, int n_in,
                              void* d_out, int out_size, void* d_ws, size_t ws_size,
                              hipStream_t stream) {
    const float* x    = (const float*)d_in[0];
    const float* wih0 = (const float*)d_in[1];
    const float* whh0 = (const float*)d_in[2];
    const float* bih0 = (const float*)d_in[3];
    const float* bhh0 = (const float*)d_in[4];
    const float* wih1 = (const float*)d_in[5];
    const float* whh1 = (const float*)d_in[6];
    const float* bih1 = (const float*)d_in[7];
    const float* bhh1 = (const float*)d_in[8];
    const float* fcw  = (const float*)d_in[9];
    const float* fcb  = (const float*)d_in[10];
    float* outp = (float*)d_out;

    // ws layout (~4.4 MB):
    char* ws = (char*)d_ws;
    unsigned* flags  = (unsigned*)ws;                         // 256*64B used (region 196608)
    ushort_t* h0pack = (ushort_t*)(ws + 196608);              // 1 MB
    ushort_t* h1pack = (ushort_t*)(ws + 196608 + 1048576);    // 1 MB
    ushort_t* xpack  = (ushort_t*)(ws + 196608 + 2097152);    // 1 MB
    float*    fcT    = (float*)(ws + 196608 + 3145728);       // 512*500*4 = 1024000

    // zero: flags + h packs (h0 = 0 both parities)
    hipMemsetAsync(ws, 0, 196608 + 2097152, stream);
    pack_x0<<<64, 256, 0, stream>>>(x, xpack);
    {
        int nel = NS * HH;
        transpose_k<<<(nel + 255) / 256, 256, 0, stream>>>(fcw, fcT, NS, HH);
    }

    hipFuncSetAttribute((const void*)gru_main,
                        hipFuncAttributeMaxDynamicSharedMemorySize, SMEMB);

    void* args[] = {(void*)&x,
                    (void*)&wih0, (void*)&whh0, (void*)&bih0, (void*)&bhh0,
                    (void*)&wih1, (void*)&whh1, (void*)&bih1, (void*)&bhh1,
                    (void*)&fcb, (void*)&fcT,
                    (void*)&xpack, (void*)&h0pack, (void*)&h1pack,
                    (void*)&flags, (void*)&outp};
    hipError_t e = hipLaunchCooperativeKernel((const void*)gru_main, dim3(NBLK), dim3(TBLK),
                                              args, SMEMB, stream);
    if (e != hipSuccess) {
        gru_main<<<dim3(NBLK), dim3(TBLK), SMEMB, stream>>>(
            x, wih0, whh0, bih0, bhh0, wih1, whh1, bih1, bhh1,
            fcb, fcT, xpack, h0pack, h1pack, flags, outp);
    }
}

// Round 9
// 3136.375 us; speedup vs baseline: 1.8409x; 1.0607x over previous
//
#include <hip/hip_runtime.h>
#include <math.h>

typedef __attribute__((ext_vector_type(8))) short short8;
typedef __attribute__((ext_vector_type(4))) float floatx4;
typedef unsigned short ushort_t;
typedef unsigned int uint32;
typedef unsigned long long u64;

#define BB 256
#define TT 250
#define NS 500
#define HH 512
#define NBLK 256
#define TBLK 512
#define PL_USH 131072u      // act plane: 16ch*16ct*64lane*8 ushorts (512K x 256 bf16)
#define CH_USH 8192u        // act chunk stride: 16ct*64*8
// split-mode (16 units/block, one weight matrix):
#define WP_USH 24576        // 16ch*3rt*64lane*8 ushorts (48 rows x 512 K)
#define SMEMB_SPLIT (WP_USH * 2 * 2)   // 98304 B
#define PPAR 393216         // partial parity stride in f32
#define NSTEP 253
// u8-mode (8 units/block, both matrices — proven R7):
#define WHI_USH 32768
#define SMEMB_U8 131072

#define WS_FLAGS   196608
#define WS_PACKS   (3 * 1048576)
#define WS_FCT     1024000
#define WS_PBUF    (4 * PPAR * 4)   // 6291456
#define WS_NEED_SPLIT ((size_t)(WS_FLAGS + WS_PACKS + WS_FCT + WS_PBUF))

// ---- bf16 split helpers (RNE) ----
__device__ __forceinline__ ushort_t f2bf(float f) {
    uint32 u = __float_as_uint(f);
    u += 0x7fffu + ((u >> 16) & 1u);
    return (ushort_t)(u >> 16);
}
__device__ __forceinline__ float bf2f(ushort_t h) { return __uint_as_float(((uint32)h) << 16); }
__device__ __forceinline__ float sigm(float x) { return 1.f / (1.f + expf(-x)); }
__device__ __forceinline__ floatx4 mfma16(short8 a, short8 b, floatx4 c) {
    return __builtin_amdgcn_mfma_f32_16x16x32_bf16(a, b, c, 0, 0, 0);
}
__device__ __forceinline__ u64 pack4(const ushort_t* a) {
    return (u64)a[0] | ((u64)a[1] << 16) | ((u64)a[2] << 32) | ((u64)a[3] << 48);
}
__device__ __forceinline__ void st_agent_u64(ushort_t* p, u64 v) {
    __hip_atomic_store((u64*)p, v, __ATOMIC_RELAXED, __HIP_MEMORY_SCOPE_AGENT);
}
__device__ __forceinline__ void st_agent_f4(float* p, floatx4 v) {
    union { floatx4 f; u64 q[2]; } cv; cv.f = v;
    u64* q = (u64*)p;
    __hip_atomic_store(q,     cv.q[0], __ATOMIC_RELAXED, __HIP_MEMORY_SCOPE_AGENT);
    __hip_atomic_store(q + 1, cv.q[1], __ATOMIC_RELAXED, __HIP_MEMORY_SCOPE_AGENT);
}

// ------------- flat one-round barrier: thread j polls block j's flag ------------------
__device__ __forceinline__ void dbar(unsigned* flags, unsigned phase, int bid) {
    asm volatile("s_waitcnt vmcnt(0)" ::: "memory");
    __syncthreads();
    if (threadIdx.x == 0)
        __hip_atomic_store(flags + ((size_t)bid << 4), phase,
                           __ATOMIC_RELAXED, __HIP_MEMORY_SCOPE_AGENT);
    if (threadIdx.x < NBLK) {
        unsigned* sp = flags + ((size_t)threadIdx.x << 4);
        while (__hip_atomic_load(sp, __ATOMIC_RELAXED, __HIP_MEMORY_SCOPE_AGENT) < phase)
            __builtin_amdgcn_s_sleep(2);
    }
    __syncthreads();
}

// ---------------- block reductions (512 thr = 8 waves) ----------------
__device__ __forceinline__ float block_max8(float v, float* scr) {
#pragma unroll
    for (int off = 32; off; off >>= 1) v = fmaxf(v, __shfl_down(v, off, 64));
    if ((threadIdx.x & 63) == 0) scr[threadIdx.x >> 6] = v;
    __syncthreads();
    if (threadIdx.x == 0) {
        float m = scr[0];
#pragma unroll
        for (int w = 1; w < 8; ++w) m = fmaxf(m, scr[w]);
        scr[16] = m;
    }
    __syncthreads();
    float r = scr[16];
    __syncthreads();
    return r;
}
__device__ __forceinline__ float2 block_sum2_8(float a, float b, float* scr) {
#pragma unroll
    for (int off = 32; off; off >>= 1) {
        a += __shfl_down(a, off, 64);
        b += __shfl_down(b, off, 64);
    }
    if ((threadIdx.x & 63) == 0) { int w = threadIdx.x >> 6; scr[w] = a; scr[8 + w] = b; }
    __syncthreads();
    if (threadIdx.x == 0) {
        float sa = 0.f, sb = 0.f;
#pragma unroll
        for (int w = 0; w < 8; ++w) { sa += scr[w]; sb += scr[8 + w]; }
        scr[16] = sa; scr[17] = sb;
    }
    __syncthreads();
    float2 r = make_float2(scr[16], scr[17]);
    __syncthreads();
    return r;
}

// ======================= SPLIT-MODE GEMM (one source, 48 rows) =======================
__device__ __forceinline__ void gemm_one(const ushort_t* __restrict__ gp,
                                         const ushort_t* whiS, const ushort_t* wloS,
                                         floatx4 (&acc)[3]) {
    short8 Bh[12], Bl[12];

#define ISSUE1(pc) do {                                                                   \
        const ushort_t* _p = gp + (size_t)(pc) * CH_USH;                                  \
        asm volatile("global_load_dwordx4 %0, %1, off sc0 sc1"                            \
                     : "=v"(Bh[(pc) % 12]) : "v"(_p));                                    \
        asm volatile("global_load_dwordx4 %0, %1, off sc0 sc1"                            \
                     : "=v"(Bl[(pc) % 12]) : "v"(_p + PL_USH));                           \
    } while (0)

    ISSUE1(0); ISSUE1(1); ISSUE1(2); ISSUE1(3); ISSUE1(4); ISSUE1(5);
    ISSUE1(6); ISSUE1(7); ISSUE1(8); ISSUE1(9); ISSUE1(10); ISSUE1(11);

    short8 w0h = *(const short8*)(whiS);
    short8 w1h = *(const short8*)(whiS + 512);
    short8 w2h = *(const short8*)(whiS + 1024);
    short8 w0l = *(const short8*)(wloS);
    short8 w1l = *(const short8*)(wloS + 512);
    short8 w2l = *(const short8*)(wloS + 1024);

#define GSTEP1(c, N) do {                                                                 \
        short8 n0h, n1h, n2h, n0l, n1l, n2l;                                              \
        if ((c) + 1 < 16) {                                                               \
            const size_t _w = (size_t)((c) + 1) * 3 * 512;                                \
            n0h = *(const short8*)(whiS + _w);                                            \
            n1h = *(const short8*)(whiS + _w + 512);                                      \
            n2h = *(const short8*)(whiS + _w + 1024);                                     \
            n0l = *(const short8*)(wloS + _w);                                            \
            n1l = *(const short8*)(wloS + _w + 512);                                      \
            n2l = *(const short8*)(wloS + _w + 1024);                                     \
        }                                                                                 \
        asm volatile("s_waitcnt vmcnt(" #N ")" ::: "memory");                             \
        __builtin_amdgcn_sched_barrier(0);                                                \
        const int _cs = (c) % 12;                                                         \
        acc[0] = mfma16(w0h, Bh[_cs], acc[0]);                                            \
        acc[1] = mfma16(w1h, Bh[_cs], acc[1]);                                            \
        acc[2] = mfma16(w2h, Bh[_cs], acc[2]);                                            \
        acc[0] = mfma16(w0h, Bl[_cs], acc[0]);                                            \
        acc[1] = mfma16(w1h, Bl[_cs], acc[1]);                                            \
        acc[2] = mfma16(w2h, Bl[_cs], acc[2]);                                            \
        acc[0] = mfma16(w0l, Bh[_cs], acc[0]);                                            \
        acc[1] = mfma16(w1l, Bh[_cs], acc[1]);                                            \
        acc[2] = mfma16(w2l, Bh[_cs], acc[2]);                                            \
        if ((c) + 12 < 16) ISSUE1((c) + 12);                                              \
        if ((c) + 1 < 16) { w0h = n0h; w1h = n1h; w2h = n2h;                              \
                            w0l = n0l; w1l = n1l; w2l = n2l; }                            \
    } while (0)

    GSTEP1(0, 22);  GSTEP1(1, 22);  GSTEP1(2, 22);  GSTEP1(3, 22);  GSTEP1(4, 22);
    GSTEP1(5, 20);  GSTEP1(6, 18);  GSTEP1(7, 16);  GSTEP1(8, 14);  GSTEP1(9, 12);
    GSTEP1(10, 10); GSTEP1(11, 8);  GSTEP1(12, 6);  GSTEP1(13, 4);  GSTEP1(14, 2);
    GSTEP1(15, 0);
#undef GSTEP1
#undef ISSUE1
}

// ======================= U8-MODE GEMM (two sources, proven R7) =======================
__device__ __forceinline__ void gemm_both(const ushort_t* __restrict__ gp,
                                          const ushort_t* __restrict__ hp,
                                          const ushort_t* whiS, const ushort_t* wloS,
                                          floatx4 (&aGI)[2], floatx4 (&aGH)[2]) {
    short8 Bh[12], Bl[12];
    const ushort_t* gpl = gp + PL_USH;
    const ushort_t* hpl = hp + PL_USH;

#define ISSUE(pc) do {                                                                    \
        const ushort_t* _ph = ((pc) < 16) ? (gp + (size_t)(pc) * CH_USH)                  \
                                          : (hp + (size_t)((pc) - 16) * CH_USH);          \
        const ushort_t* _pl = ((pc) < 16) ? (gpl + (size_t)(pc) * CH_USH)                 \
                                          : (hpl + (size_t)((pc) - 16) * CH_USH);         \
        asm volatile("global_load_dwordx4 %0, %1, off sc0 sc1"                            \
                     : "=v"(Bh[(pc) % 12]) : "v"(_ph));                                   \
        asm volatile("global_load_dwordx4 %0, %1, off sc0 sc1"                            \
                     : "=v"(Bl[(pc) % 12]) : "v"(_pl));                                   \
    } while (0)

    ISSUE(0); ISSUE(1); ISSUE(2); ISSUE(3); ISSUE(4); ISSUE(5);
    ISSUE(6); ISSUE(7); ISSUE(8); ISSUE(9); ISSUE(10);

    short8 w0h = *(const short8*)(whiS);
    short8 w1h = *(const short8*)(whiS + 512);
    short8 w0l = *(const short8*)(wloS);
    short8 w1l = *(const short8*)(wloS + 512);

#define GSTEP(c, N) do {                                                                  \
        if ((c) + 11 < 32) ISSUE((c) + 11);                                               \
        short8 n0h, n1h, n0l, n1l;                                                        \
        if ((c) + 1 < 32) {                                                               \
            const size_t _w = (size_t)(((c) + 1) * 2) * 512;                              \
            n0h = *(const short8*)(whiS + _w);                                            \
            n1h = *(const short8*)(whiS + _w + 512);                                      \
            n0l = *(const short8*)(wloS + _w);                                            \
            n1l = *(const short8*)(wloS + _w + 512);                                      \
        }                                                                                 \
        asm volatile("s_waitcnt vmcnt(" #N ")" ::: "memory");                             \
        __builtin_amdgcn_sched_barrier(0);                                                \
        const int _cs = (c) % 12;                                                         \
        floatx4 (&A)[2] = ((c) < 16) ? aGI : aGH;                                         \
        A[0] = mfma16(w0h, Bh[_cs], A[0]);                                                \
        A[1] = mfma16(w1h, Bh[_cs], A[1]);                                                \
        A[0] = mfma16(w0h, Bl[_cs], A[0]);                                                \
        A[1] = mfma16(w1h, Bl[_cs], A[1]);                                                \
        A[0] = mfma16(w0l, Bh[_cs], A[0]);                                                \
        A[1] = mfma16(w1l, Bh[_cs], A[1]);                                                \
        if ((c) + 1 < 32) { w0h = n0h; w1h = n1h; w0l = n0l; w1l = n1l; }                 \
    } while (0)

    GSTEP(0, 22);  GSTEP(1, 22);  GSTEP(2, 22);  GSTEP(3, 22);  GSTEP(4, 22);
    GSTEP(5, 22);  GSTEP(6, 22);  GSTEP(7, 22);  GSTEP(8, 22);  GSTEP(9, 22);
    GSTEP(10, 22); GSTEP(11, 22); GSTEP(12, 22); GSTEP(13, 22); GSTEP(14, 22);
    GSTEP(15, 22); GSTEP(16, 22); GSTEP(17, 22); GSTEP(18, 22); GSTEP(19, 22);
    GSTEP(20, 22); GSTEP(21, 20); GSTEP(22, 18); GSTEP(23, 16); GSTEP(24, 14);
    GSTEP(25, 12); GSTEP(26, 10); GSTEP(27, 8);  GSTEP(28, 6);  GSTEP(29, 4);
    GSTEP(30, 2);  GSTEP(31, 0);
#undef GSTEP
#undef ISSUE
}

// ---------------- shared epilogue ----------------
__device__ __forceinline__ void epilogue(char* smem_raw, int bid, int tid,
                                         const ushort_t* h1pack,
                                         const float* fcb, const float* fcT,
                                         float* out) {
    const int b = bid;
    float* sh = (float*)smem_raw;
    float* scr = sh + 512;
    const ushort_t* pk = h1pack + (size_t)1 * 2 * PL_USH;   // h1[249], parity 1
    {
        const int u = tid;
        const int uo = u >> 3, j = u & 7;
        const size_t o = ((size_t)((uo >> 2) * 16 + (b >> 4)) * 64 + (uo & 3) * 16 + (b & 15)) * 8 + j;
        sh[u] = bf2f(pk[o]) + bf2f(pk[PL_USH + o]);
    }
    __syncthreads();

    const bool valid = tid < NS;
    const int o1 = valid ? tid : 0;
    float a0 = fcb[o1];
    for (int k = 0; k < HH; ++k)
        a0 = fmaf(sh[k], fcT[(size_t)k * NS + o1], a0);
    float l0 = a0 * sigm(a0);
    float mx = block_max8(valid ? l0 : -3.4e38f, scr);
    float e0 = valid ? expf(l0 - mx) : 0.f;
    float2 s2 = block_sum2_8(e0, 0.f, scr);
    float w0 = e0 / s2.x;
    for (int it = 0; it < 30; ++it) {
        float c0v = fminf(fmaxf(w0, 0.f), 0.1f);
        float lv = w0 - c0v;
        float n0 = (c0v != 0.1f) ? c0v : 0.f;
        float2 rs = block_sum2_8(lv, n0, scr);
        w0 = c0v + rs.x / rs.y * n0;
    }
    if (valid) out[(size_t)b * NS + tid] = w0;
}

// =================== SPLIT-MODE MAIN (role-split, 16 units/block) ===================
// Roles: bid>>6 = {L0gi, L0gh, L1gi, L1gh}; UG=(bid>>1)&31; CT=bid&1.
// Step s: L0gi: gi0(s); L0gh: h0(s-1); L1gi: gi1(s-2); L1gh: h1(s-3).
__global__ void __launch_bounds__(TBLK, 2)
gru_split(const float* __restrict__ x,
          const float* __restrict__ wih0, const float* __restrict__ whh0,
          const float* __restrict__ bi0,  const float* __restrict__ bh0,
          const float* __restrict__ wih1, const float* __restrict__ whh1,
          const float* __restrict__ bi1,  const float* __restrict__ bh1,
          const float* __restrict__ fcb,  const float* __restrict__ fcT,
          ushort_t* xpack, ushort_t* h0pack, ushort_t* h1pack,
          float* Pbuf, unsigned* flags,
          float* __restrict__ out)
{
    extern __shared__ char smem_raw[];
    ushort_t* whi = (ushort_t*)smem_raw;            // 48 KB
    ushort_t* wlo = whi + WP_USH;                   // 48 KB

    const int bid = blockIdx.x, tid = threadIdx.x;
    const int role = bid >> 6;
    const int UG = (bid >> 1) & 31;
    const int CT = bid & 1;
    const int wid = tid >> 6, lane = tid & 63;
    const bool isGH = role & 1;

    {
        const float* Wsrc = (role == 0) ? wih0 : (role == 1) ? whh0
                           : (role == 2) ? wih1 : whh1;
        const int Ksrc = (role == 0) ? NS : HH;
        for (int idx = tid; idx < WP_USH; idx += TBLK) {
            const int j = idx & 7, ln = (idx >> 3) & 63, rc = idx >> 9;
            const int c = rc / 3, rt = rc - c * 3;
            const int m = ln & 15, qq = ln >> 4;
            const int k = c * 32 + qq * 8 + j;
            float v = 0.f;
            if (k < Ksrc) v = Wsrc[(size_t)(rt * HH + UG * 16 + m) * Ksrc + k];
            const ushort_t hb = f2bf(v);
            whi[idx] = hb;
            wlo[idx] = f2bf(v - bf2f(hb));
        }
    }

    float biR[4], biZ[4], biN[4], bhR[4], bhZ[4], bhN[4];
    if (isGH) {
        const float* bi = (role == 1) ? bi0 : bi1;
        const float* bh = (role == 1) ? bh0 : bh1;
#pragma unroll
        for (int r = 0; r < 4; ++r) {
            const int ugl = UG * 16 + ((lane >> 4) * 4 + r);
            biR[r] = bi[ugl]; biZ[r] = bi[HH + ugl]; biN[r] = bi[2 * HH + ugl];
            bhR[r] = bh[ugl]; bhZ[r] = bh[HH + ugl]; bhN[r] = bh[2 * HH + ugl];
        }
    }
    float hreg[4] = {0.f, 0.f, 0.f, 0.f};
    __syncthreads();

    const ushort_t* whiS = whi + (size_t)lane * 8;
    const ushort_t* wloS = wlo + (size_t)lane * 8;
    const size_t apoff = ((size_t)(CT * 8 + wid) * 64 + lane) * 8;
    float* Pmy = Pbuf + (size_t)(role >> 1) * (2 * PPAR)
               + (((size_t)(UG * 2 + CT) * 8 + wid) * 3) * 256 + (size_t)lane * 4;

    for (int s = 0; s < NSTEP; ++s) {
        bool active;
        switch (role) {
            case 0:  active = (s <= 249); break;
            case 1:  active = (s >= 1 && s <= 250); break;
            case 2:  active = (s >= 2 && s <= 251); break;
            default: active = (s >= 3 && s <= 252); break;
        }
        if (active) {
            const ushort_t* srcb = (role == 0) ? xpack : (role == 3) ? h1pack : h0pack;
            const ushort_t* src = srcb + (size_t)(s & 1) * 2 * PL_USH + apoff;

            floatx4 pr, pz, pn;
            if (isGH) {
                const float* Pr = Pmy + (size_t)((s - 1) & 1) * PPAR;
                asm volatile("global_load_dwordx4 %0, %1, off sc0 sc1" : "=v"(pr) : "v"(Pr));
                asm volatile("global_load_dwordx4 %0, %1, off sc0 sc1" : "=v"(pz) : "v"(Pr + 256));
                asm volatile("global_load_dwordx4 %0, %1, off sc0 sc1" : "=v"(pn) : "v"(Pr + 512));
            }

            floatx4 z4 = {0.f, 0.f, 0.f, 0.f};
            floatx4 acc[3] = {z4, z4, z4};
            gemm_one(src, whiS, wloS, acc);

            float4 xv0, xv1;
            const bool doX = (s <= TT - 2) && (bid * TBLK + tid < 16384);
            int xko = 0, xb = 0;
            if (doX) {
                const int gx = bid * TBLK + tid;
                xko = gx & 63; xb = gx >> 6;
                const float* xs = x + ((size_t)xb * TT + (s + 1)) * NS + xko * 8;
                if (xko < 62) { xv0 = *(const float4*)(xs); xv1 = *(const float4*)(xs + 4); }
                else {
                    float tmp[8];
#pragma unroll
                    for (int j = 0; j < 8; ++j) {
                        const int k = xko * 8 + j;
                        tmp[j] = (k < NS) ? xs[j] : 0.f;
                    }
                    xv0 = make_float4(tmp[0], tmp[1], tmp[2], tmp[3]);
                    xv1 = make_float4(tmp[4], tmp[5], tmp[6], tmp[7]);
                }
            }

            if (!isGH) {
                float* Pw = Pmy + (size_t)(s & 1) * PPAR;
                st_agent_f4(Pw,       acc[0]);
                st_agent_f4(Pw + 256, acc[1]);
                st_agent_f4(Pw + 512, acc[2]);
            } else {
                ushort_t hi4[4], lo4[4];
#pragma unroll
                for (int r = 0; r < 4; ++r) {
                    const float rr = sigm(pr[r] + biR[r] + acc[0][r] + bhR[r]);
                    const float zz = sigm(pz[r] + biZ[r] + acc[1][r] + bhZ[r]);
                    const float nn = tanhf(pn[r] + biN[r] + rr * (acc[2][r] + bhN[r]));
                    const float hv = (1.f - zz) * nn + zz * hreg[r];
                    hreg[r] = hv;
                    hi4[r] = f2bf(hv);
                    lo4[r] = f2bf(hv - bf2f(hi4[r]));
                }
                ushort_t* pk = ((role == 1) ? h0pack : h1pack)
                             + (size_t)((s - 1) & 1) * 2 * PL_USH;
                const int u0 = UG * 16 + (lane >> 4) * 4;
                const int uo = u0 >> 3, j0 = u0 & 7;
                const int b = CT * 128 + wid * 16 + (lane & 15);
                const size_t o8 = ((size_t)((uo >> 2) * 16 + (b >> 4)) * 64
                                  + (uo & 3) * 16 + (b & 15)) * 8 + j0;
                st_agent_u64(pk + o8, pack4(hi4));
                st_agent_u64(pk + PL_USH + o8, pack4(lo4));
            }

            if (doX) {
                ushort_t hi8[8], lo8[8];
                float vv[8] = {xv0.x, xv0.y, xv0.z, xv0.w, xv1.x, xv1.y, xv1.z, xv1.w};
#pragma unroll
                for (int j = 0; j < 8; ++j) {
                    hi8[j] = f2bf(vv[j]);
                    lo8[j] = f2bf(vv[j] - bf2f(hi8[j]));
                }
                ushort_t* xp = xpack + (size_t)((s + 1) & 1) * 2 * PL_USH;
                const size_t o = ((size_t)((xko >> 2) * 16 + (xb >> 4)) * 64 + (xko & 3) * 16 + (xb & 15)) * 8;
                st_agent_u64(xp + o, pack4(hi8));
                st_agent_u64(xp + o + 4, pack4(hi8 + 4));
                st_agent_u64(xp + PL_USH + o, pack4(lo8));
                st_agent_u64(xp + PL_USH + o + 4, pack4(lo8 + 4));
            }
        }
        dbar(flags, (unsigned)s + 1, bid);
    }

    epilogue(smem_raw, bid, tid, h1pack, fcb, fcT, out);
}

// =================== U8-MODE MAIN (proven R7 kernel, fallback) ===================
__global__ void __launch_bounds__(TBLK, 2)
gru_u8(const float* __restrict__ x,
       const float* __restrict__ wih0, const float* __restrict__ whh0,
       const float* __restrict__ bi0,  const float* __restrict__ bh0,
       const float* __restrict__ wih1, const float* __restrict__ whh1,
       const float* __restrict__ bi1,  const float* __restrict__ bh1,
       const float* __restrict__ fcb,  const float* __restrict__ fcT,
       ushort_t* xpack, ushort_t* h0pack, ushort_t* h1pack,
       float* Pbuf, unsigned* flags,
       float* __restrict__ out)
{
    extern __shared__ char smem_raw[];
    ushort_t* whi = (ushort_t*)smem_raw;            // 64 KB
    ushort_t* wlo = whi + WHI_USH;                  // 64 KB

    const int bid = blockIdx.x, tid = threadIdx.x;
    const int L  = bid >> 7;
    const int UG = (bid >> 1) & 63;
    const int CT = bid & 1;
    const int wid = tid >> 6, lane = tid & 63;

    {
        const float* Wgi = L ? wih1 : wih0;
        const float* Wgh = L ? whh1 : whh0;
        const int Kgi = L ? HH : NS;
        for (int idx = tid; idx < 32768; idx += TBLK) {
            const int j = idx & 7, ln = (idx >> 3) & 63, rc = idx >> 9;
            const int c = rc >> 1, rt = rc & 1;
            const int m = ln & 15, qq = ln >> 4;
            const int lr = rt * 16 + m;
            const int g = lr >> 3, u = lr & 7;
            float v = 0.f;
            if (g < 3) {
                if (c < 16) {
                    const int k = c * 32 + qq * 8 + j;
                    if (k < Kgi) v = Wgi[(size_t)(g * HH + UG * 8 + u) * Kgi + k];
                } else {
                    const int k = (c - 16) * 32 + qq * 8 + j;
                    v = Wgh[(size_t)(g * HH + UG * 8 + u) * HH + k];
                }
            }
            const ushort_t hb = f2bf(v);
            whi[idx] = hb;
            wlo[idx] = f2bf(v - bf2f(hb));
        }
    }

    const int ub = ((lane >> 4) & 1) * 4;
    float biR[4], biZ[4], biN[4], bhR[4], bhZ[4], bhN[4];
    {
        const float* bi = L ? bi1 : bi0;
        const float* bh = L ? bh1 : bh0;
#pragma unroll
        for (int p = 0; p < 4; ++p) {
            const int ugl = UG * 8 + ub + p;
            biR[p] = bi[ugl]; biZ[p] = bi[HH + ugl]; biN[p] = bi[2 * HH + ugl];
            bhR[p] = bh[ugl]; bhZ[p] = bh[HH + ugl]; bhN[p] = bh[2 * HH + ugl];
        }
    }
    float hreg[4] = {0.f, 0.f, 0.f, 0.f};
    const int chW = UG >> 2, qqW = UG & 3;
    __syncthreads();

    const ushort_t* whiS = whi + (size_t)lane * 8;
    const ushort_t* wloS = wlo + (size_t)lane * 8;
    const size_t apoff = ((size_t)(CT * 8 + wid) * 64 + lane) * 8;

    for (int s = 0; s <= TT; ++s) {
        const unsigned phase = (unsigned)s + 1;
        const bool active = L ? (s >= 1) : (s < TT);
        if (active) {
            const ushort_t *gisrc, *ghsrc;
            if (L == 0) {
                gisrc = xpack + (size_t)(s & 1) * 2 * PL_USH;
                ghsrc = h0pack + (size_t)((s - 1) & 1) * 2 * PL_USH;
            } else {
                gisrc = h0pack + (size_t)((s - 1) & 1) * 2 * PL_USH;
                ghsrc = h1pack + (size_t)(s & 1) * 2 * PL_USH;
            }
            floatx4 z4 = {0.f, 0.f, 0.f, 0.f};
            floatx4 aGI[2], aGH[2];
            aGI[0] = z4; aGI[1] = z4; aGH[0] = z4; aGH[1] = z4;
            gemm_both(gisrc + apoff, ghsrc + apoff, whiS, wloS, aGI, aGH);

            float4 xv0, xv1;
            const bool doX = (s <= TT - 2) && (bid * TBLK + tid < 16384);
            int xko = 0, xb = 0;
            if (doX) {
                const int gx = bid * TBLK + tid;
                xko = gx & 63; xb = gx >> 6;
                const float* xs = x + ((size_t)xb * TT + (s + 1)) * NS + xko * 8;
                if (xko < 62) { xv0 = *(const float4*)(xs); xv1 = *(const float4*)(xs + 4); }
                else {
                    float tmp[8];
#pragma unroll
                    for (int j = 0; j < 8; ++j) {
                        const int k = xko * 8 + j;
                        tmp[j] = (k < NS) ? xs[j] : 0.f;
                    }
                    xv0 = make_float4(tmp[0], tmp[1], tmp[2], tmp[3]);
                    xv1 = make_float4(tmp[4], tmp[5], tmp[6], tmp[7]);
                }
            }

            float zGI[4], zGH[4];
#pragma unroll
            for (int r = 0; r < 4; ++r) {
                zGI[r] = __shfl_xor(aGI[0][r], 32, 64);
                zGH[r] = __shfl_xor(aGH[0][r], 32, 64);
            }
            ushort_t* pk = L ? h1pack + (size_t)((s - 1) & 1) * 2 * PL_USH
                             : h0pack + (size_t)(s & 1) * 2 * PL_USH;
            if (lane < 32) {
                ushort_t hi4[4], lo4[4];
#pragma unroll
                for (int r = 0; r < 4; ++r) {
                    const float gir = aGI[0][r], ghr = aGH[0][r];
                    const float giz = zGI[r],    ghz = zGH[r];
                    const float gin = aGI[1][r], ghn = aGH[1][r];
                    const float rr = sigm(gir + biR[r] + ghr + bhR[r]);
                    const float zz = sigm(giz + biZ[r] + ghz + bhZ[r]);
                    const float nn = tanhf(gin + biN[r] + rr * (ghn + bhN[r]));
                    const float hv = (1.f - zz) * nn + zz * hreg[r];
                    hreg[r] = hv;
                    hi4[r] = f2bf(hv);
                    lo4[r] = f2bf(hv - bf2f(hi4[r]));
                }
                const int b = CT * 128 + wid * 16 + (lane & 15);
                const size_t o8 = ((size_t)(chW * 16 + (b >> 4)) * 64 + qqW * 16 + (b & 15)) * 8 + ub;
                st_agent_u64(pk + o8, pack4(hi4));
                st_agent_u64(pk + PL_USH + o8, pack4(lo4));
            }

            if (doX) {
                ushort_t hi8[8], lo8[8];
                float vv[8] = {xv0.x, xv0.y, xv0.z, xv0.w, xv1.x, xv1.y, xv1.z, xv1.w};
#pragma unroll
                for (int j = 0; j < 8; ++j) {
                    hi8[j] = f2bf(vv[j]);
                    lo8[j] = f2bf(vv[j] - bf2f(hi8[j]));
                }
                ushort_t* xp = xpack + (size_t)((s + 1) & 1) * 2 * PL_USH;
                const size_t o = ((size_t)((xko >> 2) * 16 + (xb >> 4)) * 64 + (xko & 3) * 16 + (xb & 15)) * 8;
                st_agent_u64(xp + o, pack4(hi8));
                st_agent_u64(xp + o + 4, pack4(hi8 + 4));
                st_agent_u64(xp + PL_USH + o, pack4(lo8));
                st_agent_u64(xp + PL_USH + o + 4, pack4(lo8 + 4));
            }
        }
        dbar(flags, phase, bid);
    }

    epilogue(smem_raw, bid, tid, h1pack, fcb, fcT, out);
}

// ---------------- prep: pack x[t=0] ----------------
__global__ void pack_x0(const float* __restrict__ x, ushort_t* __restrict__ xpack) {
    const int t = blockIdx.x * 256 + threadIdx.x;
    const int ko = t & 63, b = t >> 6;
    const float* xs = x + (size_t)b * TT * NS;
    ushort_t hi8[8], lo8[8];
#pragma unroll
    for (int j = 0; j < 8; ++j) {
        const int k = ko * 8 + j;
        const float v = (k < NS) ? xs[k] : 0.f;
        hi8[j] = f2bf(v);
        lo8[j] = f2bf(v - bf2f(hi8[j]));
    }
    const size_t o = ((size_t)((ko >> 2) * 16 + (b >> 4)) * 64 + (ko & 3) * 16 + (b & 15)) * 8;
    *(uint4*)(xpack + o) = *(uint4*)hi8;
    *(uint4*)(xpack + PL_USH + o) = *(uint4*)lo8;
}

// ---------------- prep: fc weight transpose ----------------
__global__ void transpose_k(const float* __restrict__ src, float* __restrict__ dst,
                            int G, int K) {
    int idx = blockIdx.x * 256 + threadIdx.x;
    if (idx >= G * K) return;
    int k = idx / G, g = idx - k * G;
    dst[idx] = src[(size_t)g * K + k];
}

// ---------------- launch ----------------
extern "C" void kernel_launch(void* const* d_in, const int* in_sizes, int n_in,
                              void* d_out, int out_size, void* d_ws, size_t ws_size,
                              hipStream_t stream) {
    const float* x    = (const float*)d_in[0];
    const float* wih0 = (const float*)d_in[1];
    const float* whh0 = (const float*)d_in[2];
    const float* bih0 = (const float*)d_in[3];
    const float* bhh0 = (const float*)d_in[4];
    const float* wih1 = (const float*)d_in[5];
    const float* whh1 = (const float*)d_in[6];
    const float* bih1 = (const float*)d_in[7];
    const float* bhh1 = (const float*)d_in[8];
    const float* fcw  = (const float*)d_in[9];
    const float* fcb  = (const float*)d_in[10];
    float* outp = (float*)d_out;

    char* ws = (char*)d_ws;
    unsigned* flags  = (unsigned*)ws;
    ushort_t* h0pack = (ushort_t*)(ws + WS_FLAGS);
    ushort_t* h1pack = (ushort_t*)(ws + WS_FLAGS + 1048576);
    ushort_t* xpack  = (ushort_t*)(ws + WS_FLAGS + 2097152);
    float*    fcT    = (float*)(ws + WS_FLAGS + 3145728);
    float*    Pbuf   = (float*)(ws + WS_FLAGS + 3145728 + WS_FCT);

    const bool useSplit = (ws_size == 0) || (ws_size >= WS_NEED_SPLIT);
    // ws_size==0: some harnesses pass 0 with a valid large buffer; treat as big.

    hipMemsetAsync(ws, 0, WS_FLAGS + 2097152, stream);
    pack_x0<<<64, 256, 0, stream>>>(x, xpack);
    {
        int nel = NS * HH;
        transpose_k<<<(nel + 255) / 256, 256, 0, stream>>>(fcw, fcT, NS, HH);
    }

    hipFuncSetAttribute((const void*)gru_split,
                        hipFuncAttributeMaxDynamicSharedMemorySize, SMEMB_SPLIT);
    hipFuncSetAttribute((const void*)gru_u8,
                        hipFuncAttributeMaxDynamicSharedMemorySize, SMEMB_U8);

    void* args[] = {(void*)&x,
                    (void*)&wih0, (void*)&whh0, (void*)&bih0, (void*)&bhh0,
                    (void*)&wih1, (void*)&whh1, (void*)&bih1, (void*)&bhh1,
                    (void*)&fcb, (void*)&fcT,
                    (void*)&xpack, (void*)&h0pack, (void*)&h1pack,
                    (void*)&Pbuf, (void*)&flags, (void*)&outp};
    if (useSplit) {
        hipError_t e = hipLaunchCooperativeKernel((const void*)gru_split, dim3(NBLK), dim3(TBLK),
                                                  args, SMEMB_SPLIT, stream);
        if (e != hipSuccess) {
            gru_split<<<dim3(NBLK), dim3(TBLK), SMEMB_SPLIT, stream>>>(
                x, wih0, whh0, bih0, bhh0, wih1, whh1, bih1, bhh1,
                fcb, fcT, xpack, h0pack, h1pack, Pbuf, flags, outp);
        }
    } else {
        hipError_t e = hipLaunchCooperativeKernel((const void*)gru_u8, dim3(NBLK), dim3(TBLK),
                                                  args, SMEMB_U8, stream);
        if (e != hipSuccess) {
            gru_u8<<<dim3(NBLK), dim3(TBLK), SMEMB_U8, stream>>>(
                x, wih0, whh0, bih0, bhh0, wih1, whh1, bih1, bhh1,
                fcb, fcT, xpack, h0pack, h1pack, Pbuf, flags, outp);
        }
    }
}